// Round 1
// 172.360 us; speedup vs baseline: 1.0645x; 1.0645x over previous
//
#include <hip/hip_runtime.h>
#include <hip/hip_bf16.h>

typedef unsigned int u32;
typedef unsigned short u16;
typedef __attribute__((ext_vector_type(8))) short bf16x8;   // 8 bf16 in 4 VGPRs
typedef __attribute__((ext_vector_type(4))) float f32x4;

#define DI __device__ __forceinline__

DI u16 f2bfu(float f){
  union{float f; u32 i;} u; u.f = f;
  u32 lsb = (u.i >> 16) & 1u;
  u.i += 0x7fffu + lsb;    // RNE
  return (u16)(u.i >> 16);
}

union BU { uint4 v; bf16x8 s; };

// async global -> LDS, 16B per lane. lds ptr must be wave-uniform.
DI void gld16(const void* g, void* l){
  __builtin_amdgcn_global_load_lds(
      (const __attribute__((address_space(1))) void*)g,
      (__attribute__((address_space(3))) void*)l, 16, 0, 0);
}

// ---------------- pack W_in into MFMA B-fragment order (bf16) ----------------
// B-frag for 16x16x32: lane l holds B[k = (l>>4)*8 + t][n = l&15], t=0..7.
// Wp3 : [nt 16][kk 8][lane 64][t 8]  <- W3  = W_in[512 + k][n]   (k=kk*32+...)
// Wp12: [half 2][nt 16][kk 8][lane 64][t 8] <- W_in[half*256 + k][n]
__global__ __launch_bounds__(256) void k_pack(const float* __restrict__ W_in,
                                              u16* __restrict__ Wp3,
                                              u16* __restrict__ Wp12)
{
  int idx = blockIdx.x * 256 + threadIdx.x;   // [0, 24576)
  int l = idx & 63;
  int g = idx >> 6;                            // [0, 384)
  int lq = l >> 4, lr = l & 15;
  u16 o[8];
  if (g < 128){            // W3: g = nt*8 + kk
    int nt = g >> 3, kk = g & 7;
    int n  = nt * 16 + lr;
    int k0 = 512 + kk * 32 + lq * 8;
#pragma unroll
    for (int tt = 0; tt < 8; tt++) o[tt] = f2bfu(W_in[(size_t)(k0 + tt) * 256 + n]);
    *(uint4*)(Wp3 + (size_t)idx * 8) = *(uint4*)o;
  } else {                 // W12: (g-128) = half*128 + nt*8 + kk
    int g2 = g - 128;
    int half = g2 >> 7, rem = g2 & 127;
    int nt = rem >> 3, kk = rem & 7;
    int n  = nt * 16 + lr;
    int k0 = half * 256 + kk * 32 + lq * 8;
#pragma unroll
    for (int tt = 0; tt < 8; tt++) o[tt] = f2bfu(W_in[(size_t)(k0 + tt) * 256 + n]);
    *(uint4*)(Wp12 + (size_t)g2 * 512 + (size_t)l * 8) = *(uint4*)o;
  }
}

// ---------------- k_pre: P1 = b_in + nodes@W1, P2 = nodes@W2 (bf16 MFMA) ----
// 128 blocks: bid = rt*8 + half*4 + cg. rt: 64-row tile, half: P1/P2,
// cg: 4-nt column group (64 cols each) — widens the grid 4x vs one-block-per-tile.
__global__ __launch_bounds__(256) void k_pre(
    const float* __restrict__ nodes, const float* __restrict__ b_in,
    const u16* __restrict__ Wp12, float* __restrict__ P1, float* __restrict__ P2)
{
  const int t = threadIdx.x;
  const int w = t >> 6, l = t & 63, lq = l >> 4, lr = l & 15;
  const int bid = blockIdx.x;
  const int rt = bid >> 3, half = (bid >> 2) & 1, cg = bid & 3;

  // A-frags: nodes[row = rt*64 + 16w + lr][k = kk*32 + lq*8 + t]
  bf16x8 af[8];
  {
    const float* ap = nodes + (size_t)(rt * 64 + 16 * w + lr) * 256 + lq * 8;
#pragma unroll
    for (int kk = 0; kk < 8; kk++){
      float4 x = *(const float4*)(ap + kk * 32);
      float4 y = *(const float4*)(ap + kk * 32 + 4);
      bf16x8 a;
      a[0]=(short)f2bfu(x.x); a[1]=(short)f2bfu(x.y); a[2]=(short)f2bfu(x.z); a[3]=(short)f2bfu(x.w);
      a[4]=(short)f2bfu(y.x); a[5]=(short)f2bfu(y.y); a[6]=(short)f2bfu(y.z); a[7]=(short)f2bfu(y.w);
      af[kk] = a;
    }
  }
  const uint4* wp = (const uint4*)(Wp12 + (size_t)half * 128 * 512);
  float* P = half ? P2 : P1;
#pragma unroll
  for (int ntl = 0; ntl < 4; ntl++){
    const int nt = cg * 4 + ntl;
    f32x4 acc = {0.f, 0.f, 0.f, 0.f};
#pragma unroll
    for (int kk = 0; kk < 8; kk++){
      BU bu; bu.v = wp[(nt * 8 + kk) * 64 + l];
      acc = __builtin_amdgcn_mfma_f32_16x16x32_bf16(af[kk], bu.s, acc, 0, 0, 0);
    }
    const int col = nt * 16 + lr;
    const float bv = half ? 0.f : b_in[col];
#pragma unroll
    for (int r = 0; r < 4; r++){
      const int row = rt * 64 + 16 * w + 4 * lq + r;   // C/D: row = quad*4+reg
      P[(size_t)row * 256 + col] = acc[r] + bv;
    }
  }
}

// ---------------- k_main: one block per (b,i), bf16 MFMA + fused epilogue ---
// h tile lives in the MFMA accumulators (64 VGPR) instead of a 64 KB LDS
// buffer; Wp3 is double-buffer staged into LDS via global_load_lds so the
// 4 waves share one 128 KB L2 read instead of four.
__global__ __launch_bounds__(256, 3) void k_main(
    const float* __restrict__ nodes, const float* __restrict__ edges,
    const u16* __restrict__ Wp3, const float* __restrict__ W_coef,
    const float* __restrict__ b_coef, const float* __restrict__ W_out,
    const float* __restrict__ b_out, const float* __restrict__ P1,
    const float* __restrict__ P2, float* __restrict__ out_nodes,
    float* __restrict__ out_h)
{
  __shared__ uint4 wS[2][1024];     // 2 x 16 KB: double-buffered Wp3 chunks (2 nt each)
  __shared__ float coefS[64];
  __shared__ float attnS[64];
  __shared__ float resW[4][256];    // per-wave residual partials
  __shared__ float resS[256];

  const int t = threadIdx.x;
  const int w = t >> 6, l = t & 63, lq = l >> 4, lr = l & 15;
  const int bi = blockIdx.x;          // b*64 + i
  const int b = bi >> 6, i = bi & 63;

  const char* wp3b = (const char*)Wp3;
  // stage 16 KB chunk (2 nt) of Wp3 into wS[bufi]; each wave DMAs its 4 KB
  auto stage = [&](int bufi, int ntc){
    const char* src = wp3b + (size_t)ntc * 16384;
    char* dst = (char*)&wS[bufi][0];
#pragma unroll
    for (int c = 0; c < 4; ++c)
      gld16(src + c * 4096 + w * 1024 + l * 16, dst + c * 4096 + w * 1024);
  };

  stage(0, 0);   // issue first W DMA before the A-loads so it overlaps

  // A-frags: edge rows (j = 16w + lr), f32 -> bf16 in flight
  bf16x8 af[8];
  {
    const float* ap = edges + (size_t)bi * 16384 + (size_t)(16 * w + lr) * 256 + lq * 8;
#pragma unroll
    for (int kk = 0; kk < 8; kk++){
      float4 x = *(const float4*)(ap + kk * 32);
      float4 y = *(const float4*)(ap + kk * 32 + 4);
      bf16x8 a;
      a[0]=(short)f2bfu(x.x); a[1]=(short)f2bfu(x.y); a[2]=(short)f2bfu(x.z); a[3]=(short)f2bfu(x.w);
      a[4]=(short)f2bfu(y.x); a[5]=(short)f2bfu(y.y); a[6]=(short)f2bfu(y.z); a[7]=(short)f2bfu(y.w);
      af[kk] = a;
    }
  }

  const float* p1p = P1 + (size_t)bi * 256;
  const float* p2p = P2 + (size_t)b * 64 * 256;

  f32x4 acc[16];
#pragma unroll
  for (int nt = 0; nt < 16; nt++) acc[nt] = (f32x4){0.f, 0.f, 0.f, 0.f};
  float cpart[4] = {0.f, 0.f, 0.f, 0.f};

  __syncthreads();                    // first chunk staged (barrier drains vmcnt)
  int buf = 0;
#pragma unroll
  for (int ntc = 0; ntc < 8; ntc++){
    if (ntc < 7) stage(buf ^ 1, ntc + 1);   // prefetch next chunk
#pragma unroll
    for (int nt2 = 0; nt2 < 2; nt2++){
      const int nt = ntc * 2 + nt2;
      const u16* wsb = (const u16*)&wS[buf][nt2 * 512];
#pragma unroll
      for (int kk = 0; kk < 8; kk++){
        BU bu; bu.v = *(const uint4*)(wsb + (size_t)(kk * 64 + l) * 8);
        acc[nt] = __builtin_amdgcn_mfma_f32_16x16x32_bf16(af[kk], bu.s, acc[nt], 0, 0, 0);
      }
      // fused epilogue for this 16-col slab: +P1+P2, relu, h out, coef partial
      const int col = nt * 16 + lr;
      const float p1 = p1p[col];
      const float wc = W_coef[col];
#pragma unroll
      for (int r = 0; r < 4; r++){
        const int row = 16 * w + 4 * lq + r;             // local j
        const float p2 = p2p[row * 256 + col];
        float h = acc[nt][r] + p1 + p2;
        h = h > 0.f ? h : 0.f;
        acc[nt][r] = h;                                  // keep h in registers
        out_h[((size_t)bi * 64 + row) * 256 + col] = h;  // f32 output
        cpart[r] += h * wc;
      }
    }
    __syncthreads();   // drains prefetch DMA; all waves done reading buf
    buf ^= 1;
  }

  // coef: reduce cpart over the 16 lanes of each quad (cols lr=0..15 mod 16)
#pragma unroll
  for (int r = 0; r < 4; r++){
    float v = cpart[r];
    v += __shfl_xor(v, 1, 64);
    v += __shfl_xor(v, 2, 64);
    v += __shfl_xor(v, 4, 64);
    v += __shfl_xor(v, 8, 64);
    if (lr == 0) coefS[16 * w + 4 * lq + r] = v;
  }
  __syncthreads();

  // softmax over j (threads 0..63); b_coef shifts all coefs equally
  if (t < 64){
    int j = t;
    float val = coefS[j] + b_coef[0] - (j == i ? 1e9f : 0.f);
    float m = val;
#pragma unroll
    for (int off = 32; off >= 1; off >>= 1){ float o = __shfl_xor(m, off, 64); m = m > o ? m : o; }
    float e = __expf(val - m);
    float s = e;
#pragma unroll
    for (int off = 32; off >= 1; off >>= 1) s += __shfl_xor(s, off, 64);
    attnS[j] = e / s;
  }
  __syncthreads();

  // residual from register-held h: part = sum over this thread's 4 rows,
  // then shfl over the lq groups (lanes l^16, l^32 share the same col)
  {
    const float a0 = attnS[16 * w + 4 * lq + 0];
    const float a1 = attnS[16 * w + 4 * lq + 1];
    const float a2 = attnS[16 * w + 4 * lq + 2];
    const float a3 = attnS[16 * w + 4 * lq + 3];
#pragma unroll
    for (int nt = 0; nt < 16; nt++){
      float part = a0 * acc[nt][0] + a1 * acc[nt][1] + a2 * acc[nt][2] + a3 * acc[nt][3];
      part += __shfl_xor(part, 16, 64);
      part += __shfl_xor(part, 32, 64);     // now = wave's 16-row partial for col nt*16+lr
      if (lq == (nt & 3)) resW[w][nt * 16 + lr] = part;
    }
  }
  __syncthreads();
  resS[t] = resW[0][t] + resW[1][t] + resW[2][t] + resW[3][t];
  __syncthreads();

  // new_nodes = nodes + relu(res @ W_out + b_out)  (f32)
  {
    const int d = t;
    float acco = b_out[d];
#pragma unroll 8
    for (int k4 = 0; k4 < 64; k4++){
      float4 r4 = *(const float4*)&resS[k4 * 4];
      acco += r4.x * W_out[(size_t)(k4 * 4 + 0) * 256 + d];
      acco += r4.y * W_out[(size_t)(k4 * 4 + 1) * 256 + d];
      acco += r4.z * W_out[(size_t)(k4 * 4 + 2) * 256 + d];
      acco += r4.w * W_out[(size_t)(k4 * 4 + 3) * 256 + d];
    }
    float nv = nodes[(size_t)bi * 256 + d];
    out_nodes[(size_t)bi * 256 + d] = nv + (acco > 0.f ? acco : 0.f);
  }
}

extern "C" void kernel_launch(void* const* d_in, const int* in_sizes, int n_in,
                              void* d_out, int out_size, void* d_ws, size_t ws_size,
                              hipStream_t stream)
{
  const float* nodes  = (const float*)d_in[0];
  const float* edges  = (const float*)d_in[1];
  const float* W_in   = (const float*)d_in[2];
  const float* b_in   = (const float*)d_in[3];
  const float* W_coef = (const float*)d_in[4];
  const float* b_coef = (const float*)d_in[5];
  const float* W_out  = (const float*)d_in[6];
  const float* b_out  = (const float*)d_in[7];
  (void)in_sizes; (void)n_in; (void)out_size; (void)ws_size;

  float* P1  = (float*)d_ws;           // [1024][256] f32
  float* P2  = P1 + 262144;            // [1024][256] f32
  u16*  Wp3  = (u16*)(P2 + 262144);    // 65536 bf16 (128 KB)
  u16*  Wp12 = Wp3 + 65536;            // 131072 bf16 (256 KB)

  float* out_nodes = (float*)d_out;          // [1024*256] f32
  float* out_h = out_nodes + 262144;         // [65536*256] f32

  hipLaunchKernelGGL(k_pack, dim3(96),   dim3(256), 0, stream, W_in, Wp3, Wp12);
  hipLaunchKernelGGL(k_pre,  dim3(128),  dim3(256), 0, stream, nodes, b_in, Wp12, P1, P2);
  hipLaunchKernelGGL(k_main, dim3(1024), dim3(256), 0, stream,
                     nodes, edges, Wp3, W_coef, b_coef, W_out, b_out,
                     P1, P2, out_nodes, out_h);
}